// Round 4
// baseline (650.396 us; speedup 1.0000x reference)
//
#include <hip/hip_runtime.h>
#include <stdint.h>

using u16 = unsigned short;
using u32 = unsigned int;

typedef __attribute__((ext_vector_type(8))) short s16x8;
typedef __attribute__((ext_vector_type(4))) float f32x4;

__device__ __forceinline__ float bflo(u32 u) { u32 t = u << 16; float f; __builtin_memcpy(&f, &t, 4); return f; }
__device__ __forceinline__ float bfhi(u32 u) { u32 t = u & 0xffff0000u; float f; __builtin_memcpy(&f, &t, 4); return f; }
__device__ __forceinline__ u16 f2bf(float f) {
  u32 u; __builtin_memcpy(&u, &f, 4);
  return (u16)((u + 0x7fffu + ((u >> 16) & 1u)) >> 16);
}

__device__ __forceinline__ void gload_lds16(const void* g, void* l) {
  __builtin_amdgcn_global_load_lds((const __attribute__((address_space(1))) void*)g,
                                   (__attribute__((address_space(3))) void*)l, 16, 0, 0);
}

// ---------------- transpose + fp32->bf16 pack: in [R][Cc] -> out [Cc][R] ----------------
__global__ __launch_bounds__(256)
void transpose_pack(const float* __restrict__ in, u16* __restrict__ out,
                    int R, int Cc, long in_bs, long out_bs)
{
  __shared__ float tile[32][33];
  in  += (size_t)blockIdx.z * in_bs;
  out += (size_t)blockIdx.z * out_bs;
  const int r0 = blockIdx.x * 32, c0 = blockIdx.y * 32;
  const int tx = threadIdx.x & 31, ty = threadIdx.x >> 5;   // 32 x 8
#pragma unroll
  for (int i = 0; i < 4; ++i) {
    int r = ty + i * 8;
    tile[r][tx] = in[(size_t)(r0 + r) * Cc + c0 + tx];
  }
  __syncthreads();
#pragma unroll
  for (int i = 0; i < 4; ++i) {
    int c = ty + i * 8;
    out[(size_t)(c0 + c) * R + r0 + tx] = f2bf(tile[tx][c]);
  }
}

// ---------------- LayerNorm fp32 -> bf16, C=1024, one block per row ----------------
__global__ __launch_bounds__(256)
void ln_f32_bf16(const float* __restrict__ x, const float* __restrict__ g,
                 const float* __restrict__ bta, u16* __restrict__ out)
{
  const int row = blockIdx.x, tid = threadIdx.x;
  const float4 v = ((const float4*)(x + (size_t)row * 1024))[tid];
  float s  = v.x + v.y + v.z + v.w;
  float ss = v.x * v.x + v.y * v.y + v.z * v.z + v.w * v.w;
#pragma unroll
  for (int m = 1; m < 64; m <<= 1) {
    s  += __shfl_xor(s, m);
    ss += __shfl_xor(ss, m);
  }
  __shared__ float red[8];
  const int wave = tid >> 6, lane = tid & 63;
  if (lane == 0) { red[wave] = s; red[4 + wave] = ss; }
  __syncthreads();
  s  = red[0] + red[1] + red[2] + red[3];
  ss = red[4] + red[5] + red[6] + red[7];
  const float mu  = s * (1.f / 1024.f);
  const float var = ss * (1.f / 1024.f) - mu * mu;
  const float rs  = rsqrtf(var + 1e-5f);
  const float4 gg = ((const float4*)g)[tid];
  const float4 bb = ((const float4*)bta)[tid];
  u32 w0 = (u32)f2bf((v.x - mu) * rs * gg.x + bb.x) | ((u32)f2bf((v.y - mu) * rs * gg.y + bb.y) << 16);
  u32 w1 = (u32)f2bf((v.z - mu) * rs * gg.z + bb.z) | ((u32)f2bf((v.w - mu) * rs * gg.w + bb.w) << 16);
  u32* outp = (u32*)(out + (size_t)row * 1024 + tid * 4);
  outp[0] = w0; outp[1] = w1;
}

// ---------------- 256x256 GEMM, 2-half K-tile schedule, A[M][K] bf16, B[N][K] bf16 --------
// LDS: A[2 buf][2 Khalf][256 rows][32 cols] + B same = 128 KiB. Khalf = 32 K-cols.
// 8 waves (2Mx4N), per-wave 128x64 output, acc[8][4] f32x4.
// Per tile t (2 halves): half0 {S1=t+1.A.kh1, S2=t+1.B.kh1 -> buf^1; read kh0 (12xb128);
// 32 MFMA} barrier; half1 {S3=t+2.A.kh0, S4=t+2.B.kh0 -> buf; read kh1; 32 MFMA}
// vmcnt(4) barrier. vmcnt(4) leaves t.S3/S4 outstanding; buf^1 fully staged at t+1 start.
// Mid barrier protects buf.kh0 reads (half0) from S3/S4 writes (half1).
template <int EPI>
__global__ __launch_bounds__(512, 1)
void gemm8p(const u16* __restrict__ A, const u16* __restrict__ B, void* __restrict__ Cv,
            const float* __restrict__ bias, const float* __restrict__ resid,
            int M, int N, int K, int GM)
{
  __shared__ u16 lds[65536];   // 128 KiB
  const int NT = K >> 6;
  const int tid = threadIdx.x;
  const int lane = tid & 63, wv = tid >> 6;
  const int wr = wv >> 2, wc = wv & 3;            // 2x4 wave grid
  const int r = lane & 15, kg = lane >> 4;

  // XCD-aware bijective swizzle (all grids divisible by 8), bn-major chunks
  const int nwg = gridDim.x;
  const int q = nwg >> 3;
  const int bid = blockIdx.x;
  const int sw = (bid & 7) * q + (bid >> 3);
  const int bn = sw / GM, bm = sw % GM;

  const u16* Ab = A + (size_t)bm * 256 * K;
  const u16* Bb = B + (size_t)bn * 256 * K;

  // swizzled ds_read seg: seg = kg ^ ((row>>1)&3); (row>>1)&3 == (r>>1)&3 for all m,n
  const int segx = (kg ^ ((r >> 1) & 3)) << 3;                // u16 units
  const int aoff = (wr * 128 + r) * 32 + segx;                // + m*512 + kh*8192 + buf*16384
  const int boff = 32768 + (wc * 64 + r) * 32 + segx;         // + n*512 + kh*8192 + buf*16384

  f32x4 acc[8][4];
#pragma unroll
  for (int m = 0; m < 8; ++m)
#pragma unroll
    for (int n = 0; n < 4; ++n) acc[m][n] = f32x4{0.f, 0.f, 0.f, 0.f};

  // stage one half-tile (256 rows x 32 cols, 16 KB) : linear LDS dest, pre-swizzled global src
  auto stage = [&](const u16* src, int u, int kh, int base) {
#pragma unroll
    for (int jj = 0; jj < 2; ++jj) {
      int ci = jj * 512 + tid;
      int row = ci >> 2;
      int sseg = (ci & 3) ^ ((ci >> 3) & 3);
      gload_lds16(src + (size_t)row * K + u * 64 + kh * 32 + sseg * 8, &lds[base + ci * 8]);
    }
  };

  // ---- prologue: t0 all 4 halves -> buf0 ; t1 kh0 halves -> buf1
  stage(Ab, 0, 0, 0);
  stage(Bb, 0, 0, 32768);
  stage(Ab, 0, 1, 8192);
  stage(Bb, 0, 1, 32768 + 8192);
  if (NT > 1) {
    stage(Ab, 1, 0, 16384);
    stage(Bb, 1, 0, 32768 + 16384);
    asm volatile("s_waitcnt vmcnt(4)" ::: "memory");
  } else {
    asm volatile("s_waitcnt vmcnt(0)" ::: "memory");
  }
  __builtin_amdgcn_s_barrier();
  __builtin_amdgcn_sched_barrier(0);

  for (int t = 0; t < NT; ++t) {
    const int buf = t & 1;
    const int ab = buf * 16384;
    const bool s1 = (t + 1) < NT, s2 = (t + 2) < NT;
    s16x8 av[8], bv[4];

    // ================= half 0: kh0 =================
    if (s1) {
      stage(Ab, t + 1, 1, (buf ^ 1) * 16384 + 8192);
      stage(Bb, t + 1, 1, 32768 + (buf ^ 1) * 16384 + 8192);
    }
#pragma unroll
    for (int n = 0; n < 4; ++n) bv[n] = *(const s16x8*)&lds[ab + boff + n * 512];
#pragma unroll
    for (int m = 0; m < 8; ++m) av[m] = *(const s16x8*)&lds[ab + aoff + m * 512];
    __builtin_amdgcn_s_setprio(1);
#pragma unroll
    for (int m = 0; m < 8; ++m)
#pragma unroll
      for (int n = 0; n < 4; ++n)
        acc[m][n] = __builtin_amdgcn_mfma_f32_16x16x32_bf16(av[m], bv[n], acc[m][n], 0, 0, 0);
    __builtin_amdgcn_s_setprio(0);
    __builtin_amdgcn_sched_barrier(0);
    __builtin_amdgcn_s_barrier();      // kh0 reads complete across all waves; S3/S4 may overwrite

    // ================= half 1: kh1 =================
    if (s2) {
      stage(Ab, t + 2, 0, ab);
      stage(Bb, t + 2, 0, 32768 + ab);
    }
#pragma unroll
    for (int n = 0; n < 4; ++n) bv[n] = *(const s16x8*)&lds[ab + boff + 8192 + n * 512];
#pragma unroll
    for (int m = 0; m < 8; ++m) av[m] = *(const s16x8*)&lds[ab + aoff + 8192 + m * 512];
    __builtin_amdgcn_s_setprio(1);
#pragma unroll
    for (int m = 0; m < 8; ++m)
#pragma unroll
      for (int n = 0; n < 4; ++n)
        acc[m][n] = __builtin_amdgcn_mfma_f32_16x16x32_bf16(av[m], bv[n], acc[m][n], 0, 0, 0);
    __builtin_amdgcn_s_setprio(0);
    __builtin_amdgcn_sched_barrier(0);
    if (s2) asm volatile("s_waitcnt vmcnt(4)" ::: "memory");
    else    asm volatile("s_waitcnt vmcnt(0)" ::: "memory");
    __builtin_amdgcn_s_barrier();
  }

  // ---- epilogue
#pragma unroll
  for (int m = 0; m < 8; ++m) {
#pragma unroll
    for (int n = 0; n < 4; ++n) {
#pragma unroll
      for (int j = 0; j < 4; ++j) {
        int row = bm * 256 + wr * 128 + m * 16 + kg * 4 + j;
        int col = bn * 256 + wc * 64 + n * 16 + r;
        size_t idx = (size_t)row * N + col;
        float v = acc[m][n][j];
        if constexpr (EPI == 0) {
          ((u16*)Cv)[idx] = f2bf(v);
        } else if constexpr (EPI == 1) {
          ((float*)Cv)[idx] = v + bias[col] + resid[idx];
        } else if constexpr (EPI == 2) {
          ((u16*)Cv)[idx] = f2bf(fmaxf(v + bias[col], 0.f));
        } else {
          ((float*)Cv)[idx] = v + bias[col] + resid[idx];
        }
      }
    }
  }
}

// ---------------- MFMA flash attention: one block per (b,h), 4 waves, wave w = 64 q-rows ----
__global__ __launch_bounds__(256)
void attn_mfma(const u16* __restrict__ qkv, u16* __restrict__ outc)
{
  const int bh = blockIdx.x, b = bh >> 4, h = bh & 15;
  const int tid = threadIdx.x;
  const int lane = tid & 63, w = tid >> 6;
  const int r = lane & 15, kg = lane >> 4;

  __shared__ u16 Ks[64 * 64];       // swizzled chunks
  __shared__ u16 Vt[64 * 72];       // [d][key], stride 72
  __shared__ u16 P[4][64 * 72];     // per-wave P, [qrow][key], stride 72

  const u16* qbase = qkv + (size_t)(b * 256) * 3072 + h * 64;

  s16x8 qf[4][2];
#pragma unroll
  for (int m = 0; m < 4; ++m)
#pragma unroll
    for (int ks = 0; ks < 2; ++ks)
      qf[m][ks] = *(const s16x8*)(qbase + (size_t)(w * 64 + m * 16 + r) * 3072 + ks * 32 + kg * 8);

  f32x4 of[4][4];
  float mrun[4][4], lrun[4][4];
#pragma unroll
  for (int m = 0; m < 4; ++m) {
#pragma unroll
    for (int n = 0; n < 4; ++n) of[m][n] = f32x4{0.f, 0.f, 0.f, 0.f};
#pragma unroll
    for (int j = 0; j < 4; ++j) { mrun[m][j] = -1e30f; lrun[m][j] = 0.f; }
  }

  const float cexp = 0.03125f * 1.4426950408889634f;

  for (int kt = 0; kt < 4; ++kt) {
#pragma unroll
    for (int jj = 0; jj < 2; ++jj) {
      int ci = jj * 256 + tid;
      int key = ci >> 3, seg = ci & 7;
      int sseg = seg ^ (key & 7);
      gload_lds16(qkv + (size_t)(b * 256 + kt * 64 + key) * 3072 + 1024 + h * 64 + sseg * 8,
                  &Ks[ci * 8]);
    }
    {
      int row = tid >> 2, q = tid & 3;
      const u16* vg = qkv + (size_t)(b * 256 + kt * 64 + row) * 3072 + 2048 + h * 64 + q * 16;
      union { uint4 u[2]; u16 s[16]; } vv;
      vv.u[0] = *(const uint4*)vg;
      vv.u[1] = *(const uint4*)(vg + 8);
#pragma unroll
      for (int i = 0; i < 16; ++i)
        Vt[(q * 16 + i) * 72 + row] = vv.s[i];
    }
    __syncthreads();

    if (w >= kt) {
      f32x4 s[4][4];
#pragma unroll
      for (int m = 0; m < 4; ++m)
#pragma unroll
        for (int n = 0; n < 4; ++n) s[m][n] = f32x4{0.f, 0.f, 0.f, 0.f};
#pragma unroll
      for (int ks = 0; ks < 2; ++ks) {
        s16x8 kb[4];
#pragma unroll
        for (int n = 0; n < 4; ++n) {
          int row = n * 16 + r;
          int sseg = (ks * 4 + kg) ^ (row & 7);
          kb[n] = *(const s16x8*)&Ks[row * 64 + sseg * 8];
        }
#pragma unroll
        for (int m = 0; m < 4; ++m)
#pragma unroll
          for (int n = 0; n < 4; ++n)
            s[m][n] = __builtin_amdgcn_mfma_f32_16x16x32_bf16(qf[m][ks], kb[n], s[m][n], 0, 0, 0);
      }
      if (kt == w) {
#pragma unroll
        for (int m = 0; m < 4; ++m)
#pragma unroll
          for (int n = 0; n < 4; ++n)
#pragma unroll
            for (int j = 0; j < 4; ++j)
              if (n * 16 + r > m * 16 + kg * 4 + j) s[m][n][j] = -1e30f;
      }
#pragma unroll
      for (int m = 0; m < 4; ++m) {
        float rm[4], rsc[4], ls[4];
#pragma unroll
        for (int j = 0; j < 4; ++j) {
          rm[j] = fmaxf(fmaxf(s[m][0][j], s[m][1][j]), fmaxf(s[m][2][j], s[m][3][j]));
          rm[j] = fmaxf(rm[j], __shfl_xor(rm[j], 1));
          rm[j] = fmaxf(rm[j], __shfl_xor(rm[j], 2));
          rm[j] = fmaxf(rm[j], __shfl_xor(rm[j], 4));
          rm[j] = fmaxf(rm[j], __shfl_xor(rm[j], 8));
          float mnew = fmaxf(mrun[m][j], rm[j]);
          rsc[j] = exp2f((mrun[m][j] - mnew) * cexp);
          mrun[m][j] = mnew;
          ls[j] = 0.f;
        }
#pragma unroll
        for (int n = 0; n < 4; ++n)
#pragma unroll
          for (int j = 0; j < 4; ++j) {
            float p = exp2f((s[m][n][j] - mrun[m][j]) * cexp);
            ls[j] += p;
            P[w][(m * 16 + kg * 4 + j) * 72 + n * 16 + r] = f2bf(p);
          }
#pragma unroll
        for (int j = 0; j < 4; ++j) {
          ls[j] += __shfl_xor(ls[j], 1);
          ls[j] += __shfl_xor(ls[j], 2);
          ls[j] += __shfl_xor(ls[j], 4);
          ls[j] += __shfl_xor(ls[j], 8);
          lrun[m][j] = lrun[m][j] * rsc[j] + ls[j];
        }
#pragma unroll
        for (int n = 0; n < 4; ++n)
#pragma unroll
          for (int j = 0; j < 4; ++j)
            of[m][n][j] *= rsc[j];
      }
#pragma unroll
      for (int kk = 0; kk < 2; ++kk) {
        s16x8 pa[4], vb[4];
#pragma unroll
        for (int m = 0; m < 4; ++m)
          pa[m] = *(const s16x8*)&P[w][(m * 16 + r) * 72 + kk * 32 + kg * 8];
#pragma unroll
        for (int n = 0; n < 4; ++n)
          vb[n] = *(const s16x8*)&Vt[(n * 16 + r) * 72 + kk * 32 + kg * 8];
#pragma unroll
        for (int m = 0; m < 4; ++m)
#pragma unroll
          for (int n = 0; n < 4; ++n)
            of[m][n] = __builtin_amdgcn_mfma_f32_16x16x32_bf16(pa[m], vb[n], of[m][n], 0, 0, 0);
      }
    }
    __syncthreads();
  }

#pragma unroll
  for (int m = 0; m < 4; ++m) {
    float inv[4];
#pragma unroll
    for (int j = 0; j < 4; ++j) inv[j] = 1.f / lrun[m][j];
#pragma unroll
    for (int n = 0; n < 4; ++n)
#pragma unroll
      for (int j = 0; j < 4; ++j) {
        int row = b * 256 + w * 64 + m * 16 + kg * 4 + j;
        outc[(size_t)row * 1024 + h * 64 + n * 16 + r] = f2bf(of[m][n][j] * inv[j]);
      }
  }
}

// ------------------------------------------------------------------------------------------
extern "C" void kernel_launch(void* const* d_in, const int* in_sizes, int n_in,
                              void* d_out, int out_size, void* d_ws, size_t ws_size,
                              hipStream_t stream) {
  (void)in_sizes; (void)n_in; (void)out_size; (void)ws_size;
  const float* x     = (const float*)d_in[0];
  const float* Wq    = (const float*)d_in[1];
  const float* Wk    = (const float*)d_in[2];
  const float* Wv    = (const float*)d_in[3];
  const float* Wproj = (const float*)d_in[4];
  const float* bproj = (const float*)d_in[5];
  const float* W1    = (const float*)d_in[6];
  const float* b1    = (const float*)d_in[7];
  const float* W2    = (const float*)d_in[8];
  const float* b2    = (const float*)d_in[9];
  const float* ln1g  = (const float*)d_in[10];
  const float* ln1b  = (const float*)d_in[11];
  const float* ln2g  = (const float*)d_in[12];
  const float* ln2b  = (const float*)d_in[13];
  float* out = (float*)d_out;

  char* ws = (char*)d_ws;
  u16*   WqkvT  = (u16*)(ws + 0);              // [3072][1024] bf16
  u16*   WprojT = (u16*)(ws + 6291456);        // [1024][1024]
  u16*   W1T    = (u16*)(ws + 8388608);        // [4096][1024]
  u16*   W2T    = (u16*)(ws + 16777216);       // [1024][4096]
  u16*   hb     = (u16*)(ws + 25165824);       // [16384][1024] LN1 out; later reused as attnout
  u16*   qkvb   = (u16*)(ws + 58720256);       // [16384][3072]
  float* x2     = (float*)(ws + 159383552);    // [16384][1024] f32
  u16*   h2     = (u16*)(ws + 226492416);      // [16384][1024]
  u16*   ffn1   = (u16*)(ws + 25165824);       // [16384][4096] overlays hb+qkvb (both dead by then)
  u16*   attnout = hb;

  const int M = 16384;

  transpose_pack<<<dim3(32, 2, 16), 256, 0, stream>>>(Wq, WqkvT,           1024, 64, 65536, 65536);
  transpose_pack<<<dim3(32, 2, 16), 256, 0, stream>>>(Wk, WqkvT + 1048576, 1024, 64, 65536, 65536);
  transpose_pack<<<dim3(32, 2, 16), 256, 0, stream>>>(Wv, WqkvT + 2097152, 1024, 64, 65536, 65536);
  transpose_pack<<<dim3(32, 32, 1), 256, 0, stream>>>(Wproj, WprojT, 1024, 1024, 0, 0);
  transpose_pack<<<dim3(32, 128, 1), 256, 0, stream>>>(W1, W1T, 1024, 4096, 0, 0);
  transpose_pack<<<dim3(128, 32, 1), 256, 0, stream>>>(W2, W2T, 4096, 1024, 0, 0);

  ln_f32_bf16<<<M, 256, 0, stream>>>(x, ln1g, ln1b, hb);

  // QKV: [16384,1024] x [3072,1024]^T -> bf16 ; grid = GM*GN = 64*12
  gemm8p<0><<<64 * 12, 512, 0, stream>>>(hb, WqkvT, qkvb, nullptr, nullptr, M, 3072, 1024, 64);

  attn_mfma<<<1024, 256, 0, stream>>>(qkvb, attnout);

  // proj + bias + residual(x) -> x2 f32 ; grid 64*4
  gemm8p<1><<<64 * 4, 512, 0, stream>>>(attnout, WprojT, x2, bproj, x, M, 1024, 1024, 64);

  ln_f32_bf16<<<M, 256, 0, stream>>>(x2, ln2g, ln2b, h2);

  // FFN1: relu(h2 @ W1 + b1) -> bf16 ; grid 64*16
  gemm8p<2><<<64 * 16, 512, 0, stream>>>(h2, W1T, ffn1, b1, nullptr, M, 4096, 1024, 64);

  // FFN2: ffn1 @ W2 + b2 + x2 -> out f32 ; grid 64*4
  gemm8p<3><<<64 * 4, 512, 0, stream>>>(ffn1, W2T, out, b2, x2, M, 1024, 4096, 64);
}

// Round 5
// 614.388 us; speedup vs baseline: 1.0586x; 1.0586x over previous
//
#include <hip/hip_runtime.h>
#include <stdint.h>

using u16 = unsigned short;
using u32 = unsigned int;

typedef __attribute__((ext_vector_type(8))) short s16x8;
typedef __attribute__((ext_vector_type(4))) float f32x4;

__device__ __forceinline__ float bflo(u32 u) { u32 t = u << 16; float f; __builtin_memcpy(&f, &t, 4); return f; }
__device__ __forceinline__ float bfhi(u32 u) { u32 t = u & 0xffff0000u; float f; __builtin_memcpy(&f, &t, 4); return f; }
__device__ __forceinline__ u16 f2bf(float f) {
  u32 u; __builtin_memcpy(&u, &f, 4);
  return (u16)((u + 0x7fffu + ((u >> 16) & 1u)) >> 16);
}

__device__ __forceinline__ void gload_lds16(const void* g, void* l) {
  __builtin_amdgcn_global_load_lds((const __attribute__((address_space(1))) void*)g,
                                   (__attribute__((address_space(3))) void*)l, 16, 0, 0);
}

// ---------------- transpose + fp32->bf16 pack: in [R][Cc] -> out [Cc][R] ----------------
__global__ __launch_bounds__(256)
void transpose_pack(const float* __restrict__ in, u16* __restrict__ out,
                    int R, int Cc, long in_bs, long out_bs)
{
  __shared__ float tile[32][33];
  in  += (size_t)blockIdx.z * in_bs;
  out += (size_t)blockIdx.z * out_bs;
  const int r0 = blockIdx.x * 32, c0 = blockIdx.y * 32;
  const int tx = threadIdx.x & 31, ty = threadIdx.x >> 5;   // 32 x 8
#pragma unroll
  for (int i = 0; i < 4; ++i) {
    int r = ty + i * 8;
    tile[r][tx] = in[(size_t)(r0 + r) * Cc + c0 + tx];
  }
  __syncthreads();
#pragma unroll
  for (int i = 0; i < 4; ++i) {
    int c = ty + i * 8;
    out[(size_t)(c0 + c) * R + r0 + tx] = f2bf(tile[tx][c]);
  }
}

// ---------------- LayerNorm fp32 -> bf16, C=1024, one block per row ----------------
__global__ __launch_bounds__(256)
void ln_f32_bf16(const float* __restrict__ x, const float* __restrict__ g,
                 const float* __restrict__ bta, u16* __restrict__ out)
{
  const int row = blockIdx.x, tid = threadIdx.x;
  const float4 v = ((const float4*)(x + (size_t)row * 1024))[tid];
  float s  = v.x + v.y + v.z + v.w;
  float ss = v.x * v.x + v.y * v.y + v.z * v.z + v.w * v.w;
#pragma unroll
  for (int m = 1; m < 64; m <<= 1) {
    s  += __shfl_xor(s, m);
    ss += __shfl_xor(ss, m);
  }
  __shared__ float red[8];
  const int wave = tid >> 6, lane = tid & 63;
  if (lane == 0) { red[wave] = s; red[4 + wave] = ss; }
  __syncthreads();
  s  = red[0] + red[1] + red[2] + red[3];
  ss = red[4] + red[5] + red[6] + red[7];
  const float mu  = s * (1.f / 1024.f);
  const float var = ss * (1.f / 1024.f) - mu * mu;
  const float rs  = rsqrtf(var + 1e-5f);
  const float4 gg = ((const float4*)g)[tid];
  const float4 bb = ((const float4*)bta)[tid];
  u32 w0 = (u32)f2bf((v.x - mu) * rs * gg.x + bb.x) | ((u32)f2bf((v.y - mu) * rs * gg.y + bb.y) << 16);
  u32 w1 = (u32)f2bf((v.z - mu) * rs * gg.z + bb.z) | ((u32)f2bf((v.w - mu) * rs * gg.w + bb.w) << 16);
  u32* outp = (u32*)(out + (size_t)row * 1024 + tid * 4);
  outp[0] = w0; outp[1] = w1;
}

// ---------------- 256x256 GEMM, row-half staging + asm ds_read pipeline -------------------
// LDS: A[2 buf][256 rows][64 K] + B same = 128 KiB, row stride 128B (full cache line).
// Stage granularity = 128 rows x 64 K (16KB) of one operand, CONTIGUOUS 128B per row
// (swizzle permutes 16B chunks within the row's 128B). 8 waves (2Mx4N), acc[8][4].
// Per tile t: {stage A(t+1) | asm ds_read kh0 | stage B(t+1) | lgkmcnt(0) | 32 MFMA |
//             asm ds_read kh1 | lgkmcnt(0) | 32 MFMA | vmcnt(0) | s_barrier}.
// asm ds_reads are invisible to the waitcnt pass -> no conservative vmcnt drain against
// in-flight LDS-DMA. vmcnt(0) slack: A = full tile, B = ~1.5 halves (>= latency).
// Read swizzle: LDS[row][s] holds global seg s ^ ((row>>1)&7); 8 seg-groups x 4 banks,
// 8 lanes/group for b128 = bank minimum, conflict-free.
template <int EPI>
__global__ __launch_bounds__(512, 1)
void gemm8p(const u16* __restrict__ A, const u16* __restrict__ B, void* __restrict__ Cv,
            const float* __restrict__ bias, const float* __restrict__ resid,
            int M, int N, int K, int GM)
{
  __shared__ u16 lds[65536];   // 128 KiB: A buf0 @0, A buf1 @16384, B buf0 @32768, B buf1 @49152 (u16)
  const int NT = K >> 6;
  const int tid = threadIdx.x;
  const int lane = tid & 63, wv = tid >> 6;
  const int wr = wv >> 2, wc = wv & 3;            // 2x4 wave grid
  const int r = lane & 15, kg = lane >> 4;

  // XCD-aware bijective swizzle (all grids divisible by 8), bn-major chunks
  const int nwg = gridDim.x;
  const int q = nwg >> 3;
  const int bid = blockIdx.x;
  const int sw = (bid & 7) * q + (bid >> 3);
  const int bn = sw / GM, bm = sw % GM;

  const u16* Ab = A + (size_t)bm * 256 * K;
  const u16* Bb = B + (size_t)bn * 256 * K;

  // byte addresses for asm ds_read_b128; seg(kh0) = kg ^ (r>>1), seg(kh1) = seg(kh0)^4 -> addr^64
  const u32 ldsb = (u32)(uintptr_t)lds;
  const u32 segb = (u32)((kg ^ (r >> 1)) << 4);
  const u32 abase = ldsb + (u32)((wr * 128 + r) * 128) + segb;            // + m*2048 imm, + buf*32768
  const u32 bbase = ldsb + 65536u + (u32)((wc * 64 + r) * 128) + segb;    // + n*2048 imm, + buf*32768

  f32x4 acc[8][4];
#pragma unroll
  for (int m = 0; m < 8; ++m)
#pragma unroll
    for (int n = 0; n < 4; ++n) acc[m][n] = f32x4{0.f, 0.f, 0.f, 0.f};

  // stage one row-half (128 rows x 64 K = 16KB): linear LDS dest, pre-swizzled global src,
  // each row's 128B read contiguously (seg permutation stays within the line)
  auto stage = [&](const u16* src, int u, int h, int base_u16) {
#pragma unroll
    for (int jj = 0; jj < 2; ++jj) {
      int ci = jj * 512 + tid;
      int rl = ci >> 3;
      int sseg = (ci & 7) ^ ((rl >> 1) & 7);
      gload_lds16(src + (size_t)(h * 128 + rl) * K + u * 64 + sseg * 8,
                  &lds[base_u16 + h * 8192 + ci * 8]);
    }
  };

#define DSR(d, a, o) asm volatile("ds_read_b128 %0, %1 offset:" o : "=v"(d) : "v"(a))
#define READS(aR, bR) \
  DSR(bv0, bR, "0"); DSR(bv1, bR, "2048"); DSR(bv2, bR, "4096"); DSR(bv3, bR, "6144"); \
  DSR(av0, aR, "0"); DSR(av1, aR, "2048"); DSR(av2, aR, "4096"); DSR(av3, aR, "6144"); \
  DSR(av4, aR, "8192"); DSR(av5, aR, "10240"); DSR(av6, aR, "12288"); DSR(av7, aR, "14336")
#define MM(m, n) acc[m][n] = __builtin_amdgcn_mfma_f32_16x16x32_bf16(av##m, bv##n, acc[m][n], 0, 0, 0)
#define MFMAS() \
  MM(0,0); MM(0,1); MM(0,2); MM(0,3); MM(1,0); MM(1,1); MM(1,2); MM(1,3); \
  MM(2,0); MM(2,1); MM(2,2); MM(2,3); MM(3,0); MM(3,1); MM(3,2); MM(3,3); \
  MM(4,0); MM(4,1); MM(4,2); MM(4,3); MM(5,0); MM(5,1); MM(5,2); MM(5,3); \
  MM(6,0); MM(6,1); MM(6,2); MM(6,3); MM(7,0); MM(7,1); MM(7,2); MM(7,3)

  // ---- prologue: full tile 0 -> buf0
  stage(Ab, 0, 0, 0);      stage(Ab, 0, 1, 0);
  stage(Bb, 0, 0, 32768);  stage(Bb, 0, 1, 32768);
  asm volatile("s_waitcnt vmcnt(0)" ::: "memory");
  __builtin_amdgcn_s_barrier();

  for (int t = 0; t < NT; ++t) {
    const int buf = t & 1;
    const bool s1 = (t + 1) < NT;
    const int nb = (buf ^ 1) * 16384;
    const u32 aA0 = abase + (u32)(buf * 32768);
    const u32 aB0 = bbase + (u32)(buf * 32768);
    const u32 aA1 = aA0 ^ 64u;
    const u32 aB1 = aB0 ^ 64u;

    // ---- half 0 (kh0)
    if (s1) { stage(Ab, t + 1, 0, nb); stage(Ab, t + 1, 1, nb); }
    __builtin_amdgcn_sched_barrier(0);
    {
      s16x8 av0, av1, av2, av3, av4, av5, av6, av7, bv0, bv1, bv2, bv3;
      READS(aA0, aB0);
      if (s1) { stage(Bb, t + 1, 0, 32768 + nb); stage(Bb, t + 1, 1, 32768 + nb); }
      asm volatile("s_waitcnt lgkmcnt(0)" ::: "memory");
      __builtin_amdgcn_sched_barrier(0);
      __builtin_amdgcn_s_setprio(1);
      MFMAS();
      __builtin_amdgcn_s_setprio(0);
    }
    // ---- half 1 (kh1)
    {
      s16x8 av0, av1, av2, av3, av4, av5, av6, av7, bv0, bv1, bv2, bv3;
      READS(aA1, aB1);
      asm volatile("s_waitcnt lgkmcnt(0)" ::: "memory");
      __builtin_amdgcn_sched_barrier(0);
      __builtin_amdgcn_s_setprio(1);
      MFMAS();
      __builtin_amdgcn_s_setprio(0);
    }
    __builtin_amdgcn_sched_barrier(0);
    asm volatile("s_waitcnt vmcnt(0)" ::: "memory");
    __builtin_amdgcn_s_barrier();
  }

  // ---- epilogue
#pragma unroll
  for (int m = 0; m < 8; ++m) {
#pragma unroll
    for (int n = 0; n < 4; ++n) {
#pragma unroll
      for (int j = 0; j < 4; ++j) {
        int row = bm * 256 + wr * 128 + m * 16 + kg * 4 + j;
        int col = bn * 256 + wc * 64 + n * 16 + r;
        size_t idx = (size_t)row * N + col;
        float v = acc[m][n][j];
        if constexpr (EPI == 0) {
          ((u16*)Cv)[idx] = f2bf(v);
        } else if constexpr (EPI == 1) {
          ((float*)Cv)[idx] = v + bias[col] + resid[idx];
        } else if constexpr (EPI == 2) {
          ((u16*)Cv)[idx] = f2bf(fmaxf(v + bias[col], 0.f));
        } else {
          ((float*)Cv)[idx] = v + bias[col] + resid[idx];
        }
      }
    }
  }
#undef DSR
#undef READS
#undef MM
#undef MFMAS
}

// ---------------- MFMA flash attention: one block per (b,h), 4 waves, wave w = 64 q-rows ----
__global__ __launch_bounds__(256)
void attn_mfma(const u16* __restrict__ qkv, u16* __restrict__ outc)
{
  const int bh = blockIdx.x, b = bh >> 4, h = bh & 15;
  const int tid = threadIdx.x;
  const int lane = tid & 63, w = tid >> 6;
  const int r = lane & 15, kg = lane >> 4;

  __shared__ u16 Ks[64 * 64];       // swizzled chunks
  __shared__ u16 Vt[64 * 72];       // [d][key], stride 72
  __shared__ u16 P[4][64 * 72];     // per-wave P, [qrow][key], stride 72

  const u16* qbase = qkv + (size_t)(b * 256) * 3072 + h * 64;

  s16x8 qf[4][2];
#pragma unroll
  for (int m = 0; m < 4; ++m)
#pragma unroll
    for (int ks = 0; ks < 2; ++ks)
      qf[m][ks] = *(const s16x8*)(qbase + (size_t)(w * 64 + m * 16 + r) * 3072 + ks * 32 + kg * 8);

  f32x4 of[4][4];
  float mrun[4][4], lrun[4][4];
#pragma unroll
  for (int m = 0; m < 4; ++m) {
#pragma unroll
    for (int n = 0; n < 4; ++n) of[m][n] = f32x4{0.f, 0.f, 0.f, 0.f};
#pragma unroll
    for (int j = 0; j < 4; ++j) { mrun[m][j] = -1e30f; lrun[m][j] = 0.f; }
  }

  const float cexp = 0.03125f * 1.4426950408889634f;

  for (int kt = 0; kt < 4; ++kt) {
#pragma unroll
    for (int jj = 0; jj < 2; ++jj) {
      int ci = jj * 256 + tid;
      int key = ci >> 3, seg = ci & 7;
      int sseg = seg ^ (key & 7);
      gload_lds16(qkv + (size_t)(b * 256 + kt * 64 + key) * 3072 + 1024 + h * 64 + sseg * 8,
                  &Ks[ci * 8]);
    }
    {
      int row = tid >> 2, q = tid & 3;
      const u16* vg = qkv + (size_t)(b * 256 + kt * 64 + row) * 3072 + 2048 + h * 64 + q * 16;
      union { uint4 u[2]; u16 s[16]; } vv;
      vv.u[0] = *(const uint4*)vg;
      vv.u[1] = *(const uint4*)(vg + 8);
#pragma unroll
      for (int i = 0; i < 16; ++i)
        Vt[(q * 16 + i) * 72 + row] = vv.s[i];
    }
    __syncthreads();

    if (w >= kt) {
      f32x4 s[4][4];
#pragma unroll
      for (int m = 0; m < 4; ++m)
#pragma unroll
        for (int n = 0; n < 4; ++n) s[m][n] = f32x4{0.f, 0.f, 0.f, 0.f};
#pragma unroll
      for (int ks = 0; ks < 2; ++ks) {
        s16x8 kb[4];
#pragma unroll
        for (int n = 0; n < 4; ++n) {
          int row = n * 16 + r;
          int sseg = (ks * 4 + kg) ^ (row & 7);
          kb[n] = *(const s16x8*)&Ks[row * 64 + sseg * 8];
        }
#pragma unroll
        for (int m = 0; m < 4; ++m)
#pragma unroll
          for (int n = 0; n < 4; ++n)
            s[m][n] = __builtin_amdgcn_mfma_f32_16x16x32_bf16(qf[m][ks], kb[n], s[m][n], 0, 0, 0);
      }
      if (kt == w) {
#pragma unroll
        for (int m = 0; m < 4; ++m)
#pragma unroll
          for (int n = 0; n < 4; ++n)
#pragma unroll
            for (int j = 0; j < 4; ++j)
              if (n * 16 + r > m * 16 + kg * 4 + j) s[m][n][j] = -1e30f;
      }
#pragma unroll
      for (int m = 0; m < 4; ++m) {
        float rm[4], rsc[4], ls[4];
#pragma unroll
        for (int j = 0; j < 4; ++j) {
          rm[j] = fmaxf(fmaxf(s[m][0][j], s[m][1][j]), fmaxf(s[m][2][j], s[m][3][j]));
          rm[j] = fmaxf(rm[j], __shfl_xor(rm[j], 1));
          rm[j] = fmaxf(rm[j], __shfl_xor(rm[j], 2));
          rm[j] = fmaxf(rm[j], __shfl_xor(rm[j], 4));
          rm[j] = fmaxf(rm[j], __shfl_xor(rm[j], 8));
          float mnew = fmaxf(mrun[m][j], rm[j]);
          rsc[j] = exp2f((mrun[m][j] - mnew) * cexp);
          mrun[m][j] = mnew;
          ls[j] = 0.f;
        }
#pragma unroll
        for (int n = 0; n < 4; ++n)
#pragma unroll
          for (int j = 0; j < 4; ++j) {
            float p = exp2f((s[m][n][j] - mrun[m][j]) * cexp);
            ls[j] += p;
            P[w][(m * 16 + kg * 4 + j) * 72 + n * 16 + r] = f2bf(p);
          }
#pragma unroll
        for (int j = 0; j < 4; ++j) {
          ls[j] += __shfl_xor(ls[j], 1);
          ls[j] += __shfl_xor(ls[j], 2);
          ls[j] += __shfl_xor(ls[j], 4);
          ls[j] += __shfl_xor(ls[j], 8);
          lrun[m][j] = lrun[m][j] * rsc[j] + ls[j];
        }
#pragma unroll
        for (int n = 0; n < 4; ++n)
#pragma unroll
          for (int j = 0; j < 4; ++j)
            of[m][n][j] *= rsc[j];
      }
#pragma unroll
      for (int kk = 0; kk < 2; ++kk) {
        s16x8 pa[4], vb[4];
#pragma unroll
        for (int m = 0; m < 4; ++m)
          pa[m] = *(const s16x8*)&P[w][(m * 16 + r) * 72 + kk * 32 + kg * 8];
#pragma unroll
        for (int n = 0; n < 4; ++n)
          vb[n] = *(const s16x8*)&Vt[(n * 16 + r) * 72 + kk * 32 + kg * 8];
#pragma unroll
        for (int m = 0; m < 4; ++m)
#pragma unroll
          for (int n = 0; n < 4; ++n)
            of[m][n] = __builtin_amdgcn_mfma_f32_16x16x32_bf16(pa[m], vb[n], of[m][n], 0, 0, 0);
      }
    }
    __syncthreads();
  }

#pragma unroll
  for (int m = 0; m < 4; ++m) {
    float inv[4];
#pragma unroll
    for (int j = 0; j < 4; ++j) inv[j] = 1.f / lrun[m][j];
#pragma unroll
    for (int n = 0; n < 4; ++n)
#pragma unroll
      for (int j = 0; j < 4; ++j) {
        int row = b * 256 + w * 64 + m * 16 + kg * 4 + j;
        outc[(size_t)row * 1024 + h * 64 + n * 16 + r] = f2bf(of[m][n][j] * inv[j]);
      }
  }
}

// ------------------------------------------------------------------------------------------
extern "C" void kernel_launch(void* const* d_in, const int* in_sizes, int n_in,
                              void* d_out, int out_size, void* d_ws, size_t ws_size,
                              hipStream_t stream) {
  (void)in_sizes; (void)n_in; (void)out_size; (void)ws_size;
  const float* x     = (const float*)d_in[0];
  const float* Wq    = (const float*)d_in[1];
  const float* Wk    = (const float*)d_in[2];
  const float* Wv    = (const float*)d_in[3];
  const float* Wproj = (const float*)d_in[4];
  const float* bproj = (const float*)d_in[5];
  const float* W1    = (const float*)d_in[6];
  const float* b1    = (const float*)d_in[7];
  const float* W2    = (const float*)d_in[8];
  const float* b2    = (const float*)d_in[9];
  const float* ln1g  = (const float*)d_in[10];
  const float* ln1b  = (const float*)d_in[11];
  const float* ln2g  = (const float*)d_in[12];
  const float* ln2b  = (const float*)d_in[13];
  float* out = (float*)d_out;

  char* ws = (char*)d_ws;
  u16*   WqkvT  = (u16*)(ws + 0);              // [3072][1024] bf16
  u16*   WprojT = (u16*)(ws + 6291456);        // [1024][1024]
  u16*   W1T    = (u16*)(ws + 8388608);        // [4096][1024]
  u16*   W2T    = (u16*)(ws + 16777216);       // [1024][4096]
  u16*   hb     = (u16*)(ws + 25165824);       // [16384][1024] LN1 out; later reused as attnout
  u16*   qkvb   = (u16*)(ws + 58720256);       // [16384][3072]
  float* x2     = (float*)(ws + 159383552);    // [16384][1024] f32
  u16*   h2     = (u16*)(ws + 226492416);      // [16384][1024]
  u16*   ffn1   = (u16*)(ws + 25165824);       // [16384][4096] overlays hb+qkvb (both dead by then)
  u16*   attnout = hb;

  const int M = 16384;

  transpose_pack<<<dim3(32, 2, 16), 256, 0, stream>>>(Wq, WqkvT,           1024, 64, 65536, 65536);
  transpose_pack<<<dim3(32, 2, 16), 256, 0, stream>>>(Wk, WqkvT + 1048576, 1024, 64, 65536, 65536);
  transpose_pack<<<dim3(32, 2, 16), 256, 0, stream>>>(Wv, WqkvT + 2097152, 1024, 64, 65536, 65536);
  transpose_pack<<<dim3(32, 32, 1), 256, 0, stream>>>(Wproj, WprojT, 1024, 1024, 0, 0);
  transpose_pack<<<dim3(32, 128, 1), 256, 0, stream>>>(W1, W1T, 1024, 4096, 0, 0);
  transpose_pack<<<dim3(128, 32, 1), 256, 0, stream>>>(W2, W2T, 4096, 1024, 0, 0);

  ln_f32_bf16<<<M, 256, 0, stream>>>(x, ln1g, ln1b, hb);

  // QKV: [16384,1024] x [3072,1024]^T -> bf16 ; grid = GM*GN = 64*12
  gemm8p<0><<<64 * 12, 512, 0, stream>>>(hb, WqkvT, qkvb, nullptr, nullptr, M, 3072, 1024, 64);

  attn_mfma<<<1024, 256, 0, stream>>>(qkvb, attnout);

  // proj + bias + residual(x) -> x2 f32 ; grid 64*4
  gemm8p<1><<<64 * 4, 512, 0, stream>>>(attnout, WprojT, x2, bproj, x, M, 1024, 1024, 64);

  ln_f32_bf16<<<M, 256, 0, stream>>>(x2, ln2g, ln2b, h2);

  // FFN1: relu(h2 @ W1 + b1) -> bf16 ; grid 64*16
  gemm8p<2><<<64 * 16, 512, 0, stream>>>(h2, W1T, ffn1, b1, nullptr, M, 4096, 1024, 64);

  // FFN2: ffn1 @ W2 + b2 + x2 -> out f32 ; grid 64*4
  gemm8p<3><<<64 * 4, 512, 0, stream>>>(ffn1, W2T, out, b2, x2, M, 1024, 4096, 64);
}